// Round 10
// baseline (187.559 us; speedup 1.0000x reference)
//
#include <hip/hip_runtime.h>
#include <hip/hip_bf16.h>

#define D 64            // D_IN == D_OUT == 64
#define M44 ((1ULL << 44) - 1)
#define SPILLCAP 65536

typedef __attribute__((ext_vector_type(4))) _Float16 half4;
typedef __attribute__((ext_vector_type(8))) _Float16 half8;

// ---------------------------------------------------------------------------
// k_build (r9 form, UNCHANGED): XCD-affine row-parity build + leading prep
// blocks + KS=32 line-exclusive slot stride.
// CLOSED QUESTIONS (stop re-litigating): build WRITE ~62MB is STRUCTURAL —
// survived XCD affinity (r0), nt hints (r7), and line-exclusive padding
// (r9). Build ~63us vs the 46.5us atomic wall; the gap is fabric-level and
// not source-addressable. MEASURED WALLS: ~21.5G RMW/s device atomics;
// 1 edge/thread (r10-prev); separate dispatches (r12-prev).
template <int KS>
__global__ __launch_bounds__(256) void k_build(const int* __restrict__ rowi,
                                               const int* __restrict__ coli,
                                               const float* __restrict__ ew,
                                               unsigned long long* __restrict__ packed,
                                               unsigned int* __restrict__ slots,
                                               int4* __restrict__ spill,
                                               int* __restrict__ spillCnt, int nE,
                                               int prepBlocks,
                                               const float4* __restrict__ x4,
                                               half8* __restrict__ xh8, int nv) {
    int b = blockIdx.x;
    if (b < prepBlocks) {
        // leading blocks (r5-proven): x fp32 -> fp16, UNSCALED (k_scale
        // folds dis in after build).
        int t = b * 256 + threadIdx.x;
        if (t >= nv) return;
        float4 a = x4[2 * t], bb = x4[2 * t + 1];
        half8 h;
        h[0] = (_Float16)a.x; h[1] = (_Float16)a.y; h[2] = (_Float16)a.z; h[3] = (_Float16)a.w;
        h[4] = (_Float16)bb.x; h[5] = (_Float16)bb.y; h[6] = (_Float16)bb.z; h[7] = (_Float16)bb.w;
        xh8[t] = h;
        return;
    }
    int bp = b - prepBlocks;            // prepBlocks % 8 == 0 -> XCD(b) == bp&7
    int p = bp & 7;                     // parity class this block serves
    int e = (bp >> 3) * 256 + threadIdx.x;
    if (e >= nE) return;
    int r = rowi[e];
    if ((r & 7) != p) return;           // owned by the sibling on the right XCD
    int c = coli[e];
    float w = ew[e];
    unsigned long long fx = (unsigned long long)((double)w * 4294967296.0);
    unsigned long long old = atomicAdd(&packed[r], (1ULL << 44) | fx);
    int rank = (int)(old >> 44);
    if (rank < KS) {
        int q = (int)(w * 32768.0f + 0.5f);
        if (q > 32767) q = 32767;
        slots[r * KS + rank] = ((unsigned int)c << 15) | (unsigned int)q;
    } else {                            // KS=32: P(deg>32)~1e-9, list empty
        int pI = atomicAdd(spillCnt, 1);
        if (pI < SPILLCAP) spill[pI] = make_int4(r, c, __float_as_int(w), 0);
    }
}

// lazy dis: rsqrt(1 + sum_ew) from the packed word (sums include spilled
// edges -> exact for every node).
__device__ __forceinline__ float dis_of(unsigned long long pk) {
    return rsqrtf(1.0f + (float)(pk & M44) * (1.0f / 4294967296.0f));
}

// k_scale (r8): xh[i] *= dis_i in place -> gather needs NO packed[col] load
// and NO rsqrt per edge. ~5us streaming.
__global__ __launch_bounds__(256) void k_scale(const unsigned long long* __restrict__ packed,
                                               half8* __restrict__ xh8, int nv8) {
    int t = blockIdx.x * 256 + threadIdx.x;
    if (t >= nv8) return;
    float dis = dis_of(packed[t >> 3]);   // 8 threads/row share one 8B word
    half8 h = xh8[t];
#pragma unroll
    for (int k = 0; k < 8; ++k) h[k] = (_Float16)((float)h[k] * dis);
    xh8[t] = h;
}

// branch-free 16-record message batch (r5-PROVEN): all 16 iterations run;
// invalid t has w=0 (adds 0) and col=0 (L1-resident row) -> loads issue
// back-to-back for full MLP.
template <bool H>
__device__ __forceinline__ void batch16(unsigned int rec, float wj, int j,
                                        const half4* __restrict__ xh4,
                                        const float4* __restrict__ x4,
                                        float4& acc) {
#pragma unroll
    for (int t = 0; t < 16; ++t) {
        unsigned int rt = (unsigned int)__shfl((int)rec, t, 16);
        int col = (int)(rt >> 15);
        if constexpr (H) {
            float w = (float)(rt & 32767u) * (1.0f / 32768.0f);
            half4 hv = xh4[col * 16 + j];   // dis_col folded in by k_scale
            acc.x += w * (float)hv[0]; acc.y += w * (float)hv[1];
            acc.z += w * (float)hv[2]; acc.w += w * (float)hv[3];
        } else {
            float w = __shfl(wj, t, 16);
            float4 xv = x4[col * 16 + j];
            acc.x += w * xv.x; acc.y += w * xv.y;
            acc.z += w * xv.z; acc.w += w * xv.w;
        }
    }
}

// k_gather_gemm v9: TWO NODES PER 16-LANE GROUP (r10).
// r9 analysis: gather ~55us at 2.1TB/s fetch, VALU 33% -> still
// concurrency-bound (r5's MLP win is the precedent). Block now covers 32
// nodes (grid 3128): both nodes' slot batches + self rows issue UP FRONT,
// two independent t-loop chains interleave -> ~2x rows in flight per wave.
// Phase 2: each Bs load feeds TWO output rows (o1,o2). LDS 24KB
// (Bs 16 + Ast 32x64 fp32 8) -> 6 blocks/CU; net in-flight ~1.5x.
template <int KS, bool H>
__global__ __launch_bounds__(256) void k_gather_gemm(const float* __restrict__ x,
                                                     const _Float16* __restrict__ xh,
                                                     const unsigned long long* __restrict__ packed,
                                                     const unsigned int* __restrict__ slots,
                                                     const int4* __restrict__ spill,
                                                     const int* __restrict__ spillCnt,
                                                     const float* __restrict__ W,
                                                     const float* __restrict__ bias,
                                                     float* __restrict__ out, int n) {
    __shared__ float Bs[D * D];        // 16 KB: Bs[k][o] = W[o][k], swizzled
    __shared__ float Ast[32 * D];      // 8 KB: 32-row A tile, swizzled slots
    float4* Ast4 = (float4*)Ast;
    int tid = threadIdx.x;

    // Phase 0: stage W (issue first; overlaps the gather's global loads).
    // Chunk-swizzle by kc -> exactly 2 lanes/bank on ds_write (free, m136).
    const float4* W4 = (const float4*)W;
#pragma unroll
    for (int v = 0; v < 4; ++v) {
        int idx = tid + v * 256;       // 0..1023
        int o  = idx >> 4;             // out-ch 0..63
        int kc = idx & 15;
        float4 wv = W4[idx];
        int gq = o >> 2, oo = o & 3;
        int cpos = 4 * ((gq + kc) & 15) + oo;
        Bs[(4 * kc + 0) * 64 + cpos] = wv.x;
        Bs[(4 * kc + 1) * 64 + cpos] = wv.y;
        Bs[(4 * kc + 2) * 64 + cpos] = wv.z;
        Bs[(4 * kc + 3) * 64 + cpos] = wv.w;
    }

    // Phase 1: parity-remapped (block -> XCD b&7 handles nodes ≡ b&7 mod 8,
    // same-L2 slot lines the build dirtied). Group grp owns class-local
    // nodes liA = q*32+grp and liB = liA+16.
    int j   = tid & 15;
    int grp = tid >> 4;                // 0..15
    int cls = blockIdx.x & 7;
    int q   = blockIdx.x >> 3;
    int liA = q * 32 + grp;
    int iA  = (liA << 3) + cls;
    int iB  = ((liA + 16) << 3) + cls;
    bool vA = iA < n, vB = iB < n;

    const float4* x4 = (const float4*)x;
    const half4*  xh4 = (const half4*)xh;
    float4 accA = make_float4(0.f, 0.f, 0.f, 0.f);
    float4 accB = make_float4(0.f, 0.f, 0.f, 0.f);

    // issue ALL independent head loads up front: pkA,pkB, selfA,selfB,
    // slot batch A, slot batch B -> 6 memory ops in flight before any use.
    unsigned long long pkA = vA ? packed[iA] : 0ULL;
    unsigned long long pkB = vB ? packed[iB] : 0ULL;
    half4 hiA{}, hiB{}; float4 xiA = accA, xiB = accA;
    if (vA) { if constexpr (H) hiA = xh4[iA * 16 + j]; else xiA = x4[iA * 16 + j]; }
    if (vB) { if constexpr (H) hiB = xh4[iB * 16 + j]; else xiB = x4[iB * 16 + j]; }
    int rawA = (int)(pkA >> 44), rawB = (int)(pkB >> 44);
    int cA = rawA < KS ? rawA : KS;
    int cB = rawB < KS ? rawB : KS;
    unsigned int recA = 0u, recB = 0u;
    float wjA = 0.f, wjB = 0.f;
    if (j < cA) {
        recA = slots[iA * KS + j];
        if constexpr (!H) wjA = (float)(recA & 32767u) * (1.0f / 32768.0f) * dis_of(packed[recA >> 15]);
    }
    if (j < cB) {
        recB = slots[iB * KS + j];
        if constexpr (!H) wjB = (float)(recB & 32767u) * (1.0f / 32768.0f) * dis_of(packed[recB >> 15]);
    }
    batch16<H>(recA, wjA, j, xh4, x4, accA);
    batch16<H>(recB, wjB, j, xh4, x4, accB);
    // rare tail batches (P(deg>16) ~ 2.7%)
    for (int off = 16; off < cA; off += 16) {
        unsigned int r2 = 0u; float w2 = 0.f;
        if (off + j < cA) {
            r2 = slots[iA * KS + off + j];
            if constexpr (!H) w2 = (float)(r2 & 32767u) * (1.0f / 32768.0f) * dis_of(packed[r2 >> 15]);
        }
        batch16<H>(r2, w2, j, xh4, x4, accA);
    }
    for (int off = 16; off < cB; off += 16) {
        unsigned int r2 = 0u; float w2 = 0.f;
        if (off + j < cB) {
            r2 = slots[iB * KS + off + j];
            if constexpr (!H) w2 = (float)(r2 & 32767u) * (1.0f / 32768.0f) * dis_of(packed[r2 >> 15]);
        }
        batch16<H>(r2, w2, j, xh4, x4, accB);
    }
    // spill scan (KS=32: essentially never taken)
    if (rawA > KS || rawB > KS) {
        int total = *spillCnt;
        if (total > SPILLCAP) total = SPILLCAP;
        for (int sp = 0; sp < total; ++sp) {
            int4 v = spill[sp];
            float4* acc = (v.x == iA) ? &accA : (v.x == iB ? &accB : nullptr);
            if (acc) {
                if constexpr (H) {
                    float w = __int_as_float(v.z);   // dis_col folded in xh'
                    half4 hv = xh4[v.y * 16 + j];
                    acc->x += w * (float)hv[0]; acc->y += w * (float)hv[1];
                    acc->z += w * (float)hv[2]; acc->w += w * (float)hv[3];
                } else {
                    float w = __int_as_float(v.z) * dis_of(packed[v.y]);
                    float4 xv = x4[v.y * 16 + j];
                    acc->x += w * xv.x; acc->y += w * xv.y;
                    acc->z += w * xv.z; acc->w += w * xv.w;
                }
            }
        }
    }
    // epilogues
    if (vA) {
        float di = dis_of(pkA);
        if constexpr (H) {
            accA.x = di * ((float)hiA[0] + accA.x); accA.y = di * ((float)hiA[1] + accA.y);
            accA.z = di * ((float)hiA[2] + accA.z); accA.w = di * ((float)hiA[3] + accA.w);
        } else {
            accA.x = di * (di * xiA.x + accA.x); accA.y = di * (di * xiA.y + accA.y);
            accA.z = di * (di * xiA.z + accA.z); accA.w = di * (di * xiA.w + accA.w);
        }
    }
    if (vB) {
        float di = dis_of(pkB);
        if constexpr (H) {
            accB.x = di * ((float)hiB[0] + accB.x); accB.y = di * ((float)hiB[1] + accB.y);
            accB.z = di * ((float)hiB[2] + accB.z); accB.w = di * ((float)hiB[3] + accB.w);
        } else {
            accB.x = di * (di * xiB.x + accB.x); accB.y = di * (di * xiB.y + accB.y);
            accB.z = di * (di * xiB.z + accB.z); accB.w = di * (di * xiB.w + accB.w);
        }
    }
    Ast4[grp * 16 + ((j + (grp >> 2)) & 15)] = accA;
    Ast4[(grp + 16) * 16 + ((j + ((grp + 16) >> 2)) & 15)] = accB;
    __syncthreads();                   // covers Bs staging + Ast tile

    // Phase 2: 32x64 mini-GEMM; thread handles rows (row, row+16), out-chs
    // 4cg..4cg+3 — each Bs read feeds BOTH rows.
    int row = tid >> 4;
    int cg  = tid & 15;
    float4 o1 = ((const float4*)bias)[cg];
    float4 o2 = o1;
#pragma unroll 4
    for (int kc = 0; kc < 16; ++kc) {
        float4 a1 = Ast4[row * 16 + ((kc + (row >> 2)) & 15)];
        float4 a2 = Ast4[(row + 16) * 16 + ((kc + ((row + 16) >> 2)) & 15)];
        int cp = 4 * ((cg + kc) & 15);             // read swizzle matches staging
        float4 b0 = *(const float4*)&Bs[(4 * kc + 0) * 64 + cp];
        float4 b1 = *(const float4*)&Bs[(4 * kc + 1) * 64 + cp];
        float4 b2 = *(const float4*)&Bs[(4 * kc + 2) * 64 + cp];
        float4 b3 = *(const float4*)&Bs[(4 * kc + 3) * 64 + cp];
        o1.x += a1.x * b0.x + a1.y * b1.x + a1.z * b2.x + a1.w * b3.x;
        o1.y += a1.x * b0.y + a1.y * b1.y + a1.z * b2.y + a1.w * b3.y;
        o1.z += a1.x * b0.z + a1.y * b1.z + a1.z * b2.z + a1.w * b3.z;
        o1.w += a1.x * b0.w + a1.y * b1.w + a1.z * b2.w + a1.w * b3.w;
        o2.x += a2.x * b0.x + a2.y * b1.x + a2.z * b2.x + a2.w * b3.x;
        o2.y += a2.x * b0.y + a2.y * b1.y + a2.z * b2.y + a2.w * b3.y;
        o2.z += a2.x * b0.z + a2.y * b1.z + a2.z * b2.z + a2.w * b3.z;
        o2.w += a2.x * b0.w + a2.y * b1.w + a2.z * b2.w + a2.w * b3.w;
    }
    int r1 = ((q * 32 + row) << 3) + cls;
    int r2 = ((q * 32 + 16 + row) << 3) + cls;
    if (r1 < n) ((float4*)out)[r1 * 16 + cg] = o1;
    if (r2 < n) ((float4*)out)[r2 * 16 + cg] = o2;
}

extern "C" void kernel_launch(void* const* d_in, const int* in_sizes, int n_in,
                              void* d_out, int out_size, void* d_ws, size_t ws_size,
                              hipStream_t stream) {
    const float* x    = (const float*)d_in[0];
    const int*   ei   = (const int*)d_in[1];   // [2*E] flat: rows then cols
    const float* ew   = (const float*)d_in[2];
    const float* W    = (const float*)d_in[3];
    const float* bias = (const float*)d_in[4];
    float* out = (float*)d_out;

    int n  = in_sizes[0] / D;   // 100000
    int nE = in_sizes[2];       // 1000000
    const int* rowi = ei;
    const int* coli = ei + nE;

    // aligned workspace: packed | pad | spillCnt(128B) | slots(128B-aligned)
    // | spill | xh(fp16)
    char* base = (char*)d_ws;
    size_t off_spillCnt = ((size_t)n * 8 + 127) & ~(size_t)127;
    size_t off_slots = off_spillCnt + 128;
    auto mkNeed = [&](int KS, int withH) {
        size_t o = off_slots + (size_t)n * KS * 4 + (size_t)SPILLCAP * 16;
        return o + (withH ? (size_t)n * D * 2 : 0);
    };

    int KS, useH;
    if (ws_size >= mkNeed(32, 1))      { KS = 32; useH = 1; }
    else if (ws_size >= mkNeed(24, 1)) { KS = 24; useH = 1; }
    else                               { KS = 24; useH = 0; }

    unsigned long long* packed = (unsigned long long*)base;
    int* spillCnt = (int*)(base + off_spillCnt);
    unsigned int* slots = (unsigned int*)(base + off_slots);
    int4* spill = (int4*)(base + off_slots + (size_t)n * KS * 4);
    _Float16* xh = (_Float16*)(base + off_slots + (size_t)n * KS * 4 + (size_t)SPILLCAP * 16);

    int gE = (nE + 255) / 256;
    int buildBlocks = gE * 8;
    int nv = n * D / 8;         // 800000 half8s
    int prepBlocks = useH ? ((((nv + 255) / 256) + 7) & ~7) : 0;  // %8==0 pad
    int nPerClass = (n + 7) / 8;
    int gT = 8 * ((nPerClass + 31) / 32);   // 2 nodes/group: 3128 blocks
    int nv8 = n * 8;

    hipMemsetAsync(packed, 0, off_slots, stream);   // packed + pad + spillCnt
    if (KS == 32) {
        k_build<32><<<prepBlocks + buildBlocks, 256, 0, stream>>>(
            rowi, coli, ew, packed, slots, spill, spillCnt, nE,
            prepBlocks, (const float4*)x, (half8*)xh, nv);
        k_scale<<<(nv8 + 255) / 256, 256, 0, stream>>>(packed, (half8*)xh, nv8);
        k_gather_gemm<32, true><<<gT, 256, 0, stream>>>(x, xh, packed, slots, spill, spillCnt, W, bias, out, n);
    } else if (useH) {
        k_build<24><<<prepBlocks + buildBlocks, 256, 0, stream>>>(
            rowi, coli, ew, packed, slots, spill, spillCnt, nE,
            prepBlocks, (const float4*)x, (half8*)xh, nv);
        k_scale<<<(nv8 + 255) / 256, 256, 0, stream>>>(packed, (half8*)xh, nv8);
        k_gather_gemm<24, true><<<gT, 256, 0, stream>>>(x, xh, packed, slots, spill, spillCnt, W, bias, out, n);
    } else {
        k_build<24><<<buildBlocks, 256, 0, stream>>>(
            rowi, coli, ew, packed, slots, spill, spillCnt, nE,
            0, (const float4*)x, (half8*)xh, nv);
        k_gather_gemm<24, false><<<gT, 256, 0, stream>>>(x, xh, packed, slots, spill, spillCnt, W, bias, out, n);
    }
}

// Round 11
// 176.356 us; speedup vs baseline: 1.0635x; 1.0635x over previous
//
#include <hip/hip_runtime.h>
#include <hip/hip_bf16.h>

#define D 64            // D_IN == D_OUT == 64
#define K 24            // slots/node; deg~Poisson(10): P(>24)~3e-5 -> ~10 spill edges (inline, exact)
#define M44 ((1ULL << 44) - 1)
#define SPILLCAP 65536

typedef __attribute__((ext_vector_type(4))) _Float16 half4;
typedef __attribute__((ext_vector_type(8))) _Float16 half8;

// ===========================================================================
// MEASURED-BEST CONFIG (175.7us, round 6 bench) — reverted to after r7-r10
// all failed to beat it. CLOSED NEGATIVE RESULTS (do not re-litigate):
//  - build WRITE ~62MB is STRUCTURAL: survived XCD affinity (r0), nt hints
//    (r7, no WRITE delta), line-exclusive KS=32 padding (r9, no delta).
//  - build ~63us vs 46.5us atomic wall: gap is fabric-level.
//  - gather nt loads REGRESS (r4: latency at dep-chain head).
//  - dis-fold + k_scale is NET-ZERO (r8: -3 gather, +5 serial scale).
//  - parity-remapped gather grid: neutral (r9).
//  - 2 nodes/16-lane-group: REGRESSION (r10: chains serialize, -10us).
// PROVEN WINS kept here: XCD-affine row-parity build (r1); prep blocks at
// grid FRONT (r5); fp16 x (r1); branch-free t-loop MLP (r5); Bs staging
// swizzle 2-way banks (r1); hoisted self-row load (r5).
// MEASURED WALLS: ~21.5G RMW/s device atomics -> 46.5us floor /1M edges;
// 1 edge/thread; separate dispatches; ~54us fixed harness overhead.
// ===========================================================================
__global__ __launch_bounds__(256) void k_build(const int* __restrict__ rowi,
                                               const int* __restrict__ coli,
                                               const float* __restrict__ ew,
                                               unsigned long long* __restrict__ packed,
                                               unsigned int* __restrict__ slots,
                                               int4* __restrict__ spill,
                                               int* __restrict__ spillCnt, int nE,
                                               int prepBlocks,
                                               const float4* __restrict__ x4,
                                               half8* __restrict__ xh8, int nv) {
    int b = blockIdx.x;
    if (b < prepBlocks) {
        // leading blocks (r5-proven: front placement overlaps the atomic
        // wall): x fp32 -> fp16 (2^-11 rel err -> ~2e-4 on out, invisible).
        int t = b * 256 + threadIdx.x;
        if (t >= nv) return;
        float4 a = x4[2 * t], bb = x4[2 * t + 1];
        half8 h;
        h[0] = (_Float16)a.x; h[1] = (_Float16)a.y; h[2] = (_Float16)a.z; h[3] = (_Float16)a.w;
        h[4] = (_Float16)bb.x; h[5] = (_Float16)bb.y; h[6] = (_Float16)bb.z; h[7] = (_Float16)bb.w;
        xh8[t] = h;
        return;
    }
    int bp = b - prepBlocks;
    int p = bp & 7;                     // parity class this block serves
    int e = (bp >> 3) * 256 + threadIdx.x;
    if (e >= nE) return;
    int r = rowi[e];
    if ((r & 7) != p) return;           // owned by the sibling on the right XCD
    int c = coli[e];
    float w = ew[e];
    unsigned long long fx = (unsigned long long)((double)w * 4294967296.0);
    unsigned long long old = atomicAdd(&packed[r], (1ULL << 44) | fx);
    int rank = (int)(old >> 44);
    if (rank < K) {
        int q = (int)(w * 32768.0f + 0.5f);
        if (q > 32767) q = 32767;
        slots[r * K + rank] = ((unsigned int)c << 15) | (unsigned int)q;
    } else {
        int pI = atomicAdd(spillCnt, 1);
        if (pI < SPILLCAP) spill[pI] = make_int4(r, c, __float_as_int(w), 0);
    }
}

// lazy dis: rsqrt(1 + sum_ew) straight from the packed word (exact for all
// nodes: sums include spilled edges). 44-bit fixed -> float: ~1e-7 on dis.
__device__ __forceinline__ float dis_of(unsigned long long pk) {
    return rsqrtf(1.0f + (float)(pk & M44) * (1.0f / 4294967296.0f));
}

// k_gather_gemm (r5-PROVEN, measured best): 6250 blocks, 1 node per 16-lane
// group; Bs in LDS w/ 2-way-bank staging swizzle; BRANCH-FREE inner t-loop
// (invalid t: w=0 adds zero, col=0 is L1-resident -> 16 row-loads issue
// back-to-back = full MLP, the single biggest gather win, r5: -84->?<57us);
// hoisted self-row load in flight during the whole slot loop.
template <bool H>
__global__ __launch_bounds__(256) void k_gather_gemm(const float* __restrict__ x,
                                                     const _Float16* __restrict__ xh,
                                                     const unsigned long long* __restrict__ packed,
                                                     const unsigned int* __restrict__ slots,
                                                     const int4* __restrict__ spill,
                                                     const int* __restrict__ spillCnt,
                                                     const float* __restrict__ W,
                                                     const float* __restrict__ bias,
                                                     float* __restrict__ out, int n) {
    __shared__ float Bs[D * D];        // 16 KB: Bs[k][o] = W[o][k], swizzled
    __shared__ float Ast[16 * D];      // 4 KB: 16-row A tile, swizzled slots
    float4* Ast4 = (float4*)Ast;
    int tid = threadIdx.x;

    // Phase 0: stage W (issue first; overlaps the gather's global loads).
    // Chunk-swizzle by kc -> exactly 2 lanes/bank on ds_write (free, m136).
    const float4* W4 = (const float4*)W;
#pragma unroll
    for (int v = 0; v < 4; ++v) {
        int idx = tid + v * 256;       // 0..1023
        int o  = idx >> 4;             // out-ch 0..63
        int kc = idx & 15;
        float4 wv = W4[idx];
        int gq = o >> 2, oo = o & 3;
        int cpos = 4 * ((gq + kc) & 15) + oo;
        Bs[(4 * kc + 0) * 64 + cpos] = wv.x;
        Bs[(4 * kc + 1) * 64 + cpos] = wv.y;
        Bs[(4 * kc + 2) * 64 + cpos] = wv.z;
        Bs[(4 * kc + 3) * 64 + cpos] = wv.w;
    }

    // Phase 1: gather (one node per 16-lane group)
    int j   = tid & 15;                // k-chunk lane
    int grp = tid >> 4;                // 0..15
    int i0  = blockIdx.x * 16;
    int i   = i0 + grp;

    float4 acc = make_float4(0.f, 0.f, 0.f, 0.f);
    const float4* x4 = (const float4*)x;
    const half4*  xh4 = (const half4*)xh;
    if (i < n) {
        unsigned long long pk = packed[i];
        // hoisted self-row load: in flight during the whole slot loop
        half4 hi; float4 xi;
        if constexpr (H) hi = xh4[i * 16 + j]; else xi = x4[i * 16 + j];
        int rawc = (int)(pk >> 44);
        int c_n = rawc < K ? rawc : K;
        int s = i * K;
        for (int off = 0; off < c_n; off += 16) {
            int idx = off + j;
            unsigned int rec = 0u;
            float wj = 0.f;
            if (idx < c_n) {           // invalid lanes: rec=0, wj=0 (must NOT
                rec = slots[s + idx];  // read stale slots beyond c_n)
                wj = (float)(rec & 32767u) * (1.0f / 32768.0f) * dis_of(packed[rec >> 15]);
            }
            // BRANCH-FREE: all 16 iterations run; invalid t has w=0 (adds 0)
            // and col=0 (x row 0, L1-resident broadcast). Loads issue
            // back-to-back -> full MLP.
#pragma unroll
            for (int t = 0; t < 16; ++t) {
                int col = (int)((unsigned int)__shfl((int)rec, t, 16) >> 15);
                float w = __shfl(wj, t, 16);
                if constexpr (H) {
                    half4 hv = xh4[col * 16 + j];
                    acc.x += w * (float)hv[0]; acc.y += w * (float)hv[1];
                    acc.z += w * (float)hv[2]; acc.w += w * (float)hv[3];
                } else {
                    float4 xv = x4[col * 16 + j];
                    acc.x += w * xv.x; acc.y += w * xv.y;
                    acc.z += w * xv.z; acc.w += w * xv.w;
                }
            }
        }
        if (rawc > K) {                // statistically ~10 edges in the graph
            int total = *spillCnt;
            if (total > SPILLCAP) total = SPILLCAP;
            for (int sp = 0; sp < total; ++sp) {
                int4 v = spill[sp];    // broadcast (same addr all lanes)
                if (v.x == i) {
                    float w = __int_as_float(v.z) * dis_of(packed[v.y]);
                    if constexpr (H) {
                        half4 hv = xh4[v.y * 16 + j];
                        acc.x += w * (float)hv[0]; acc.y += w * (float)hv[1];
                        acc.z += w * (float)hv[2]; acc.w += w * (float)hv[3];
                    } else {
                        float4 xv = x4[v.y * 16 + j];
                        acc.x += w * xv.x; acc.y += w * xv.y;
                        acc.z += w * xv.z; acc.w += w * xv.w;
                    }
                }
            }
        }
        float di = dis_of(pk);
        if constexpr (H) {
            acc.x = di * (di * (float)hi[0] + acc.x);
            acc.y = di * (di * (float)hi[1] + acc.y);
            acc.z = di * (di * (float)hi[2] + acc.z);
            acc.w = di * (di * (float)hi[3] + acc.w);
        } else {
            acc.x = di * (di * xi.x + acc.x);
            acc.y = di * (di * xi.y + acc.y);
            acc.z = di * (di * xi.z + acc.z);
            acc.w = di * (di * xi.w + acc.w);
        }
    }
    Ast4[grp * 16 + ((j + (grp >> 2)) & 15)] = acc;   // swizzled slot
    __syncthreads();                   // covers Bs staging + Ast tile

    // Phase 2: 16x64 mini-GEMM (thread: row=grp', out-chs 4j..4j+3)
    int row = tid >> 4;
    int cg  = tid & 15;
    float4 oacc = ((const float4*)bias)[cg];
#pragma unroll 4
    for (int kc = 0; kc < 16; ++kc) {
        float4 a4 = Ast4[row * 16 + ((kc + (row >> 2)) & 15)];
        int cp = 4 * ((cg + kc) & 15);             // read swizzle matches staging
        float4 b0 = *(const float4*)&Bs[(4 * kc + 0) * 64 + cp];
        float4 b1 = *(const float4*)&Bs[(4 * kc + 1) * 64 + cp];
        float4 b2 = *(const float4*)&Bs[(4 * kc + 2) * 64 + cp];
        float4 b3 = *(const float4*)&Bs[(4 * kc + 3) * 64 + cp];
        oacc.x += a4.x * b0.x + a4.y * b1.x + a4.z * b2.x + a4.w * b3.x;
        oacc.y += a4.x * b0.y + a4.y * b1.y + a4.z * b2.y + a4.w * b3.y;
        oacc.z += a4.x * b0.z + a4.y * b1.z + a4.z * b2.z + a4.w * b3.z;
        oacc.w += a4.x * b0.w + a4.y * b1.w + a4.z * b2.w + a4.w * b3.w;
    }
    int r = i0 + row;
    if (r < n) ((float4*)out)[r * 16 + cg] = oacc;
}

extern "C" void kernel_launch(void* const* d_in, const int* in_sizes, int n_in,
                              void* d_out, int out_size, void* d_ws, size_t ws_size,
                              hipStream_t stream) {
    const float* x    = (const float*)d_in[0];
    const int*   ei   = (const int*)d_in[1];   // [2*E] flat: rows then cols
    const float* ew   = (const float*)d_in[2];
    const float* W    = (const float*)d_in[3];
    const float* bias = (const float*)d_in[4];
    float* out = (float*)d_out;

    int n  = in_sizes[0] / D;   // 100000
    int nE = in_sizes[2];       // 1000000
    const int* rowi = ei;
    const int* coli = ei + nE;

    // workspace: packed | spillCnt | slots | spill | xh(fp16)
    char* w = (char*)d_ws;
    unsigned long long* packed = (unsigned long long*)w; w += (size_t)n * 8;
    int* spillCnt = (int*)w;                             w += 64;
    unsigned int* slots = (unsigned int*)w;              w += (size_t)n * K * 4;
    int4* spill = (int4*)w;                              w += (size_t)SPILLCAP * 16;
    _Float16* xh = (_Float16*)w;

    size_t need = (size_t)n * 8 + 64 + (size_t)n * K * 4 + (size_t)SPILLCAP * 16
                + (size_t)n * D * 2;
    int useH = ws_size >= need ? 1 : 0;

    int gE = (nE + 255) / 256;
    int buildBlocks = gE * 8;
    int nv = n * D / 8;         // 800000 half8s
    int prepBlocks = useH ? (nv + 255) / 256 : 0;   // leading blocks
    int gT = (n + 15) / 16;     // 6250 blocks: 16 nodes/block, 1 node/group

    hipMemsetAsync(packed, 0, (size_t)n * 8 + 64, stream);   // packed + spillCnt
    k_build<<<prepBlocks + buildBlocks, 256, 0, stream>>>(
        rowi, coli, ew, packed, slots, spill, spillCnt, nE,
        prepBlocks, (const float4*)x, (half8*)xh, nv);
    if (useH)
        k_gather_gemm<true><<<gT, 256, 0, stream>>>(x, xh, packed, slots, spill, spillCnt, W, bias, out, n);
    else
        k_gather_gemm<false><<<gT, 256, 0, stream>>>(x, xh, packed, slots, spill, spillCnt, W, bias, out, n);
}